// Round 4
// baseline (229.727 us; speedup 1.0000x reference)
//
#include <hip/hip_runtime.h>
#include <math.h>

#define T_TOK 4096
#define A_DIM 1024
#define E_DIM 512
#define N_SPAN 32768
#define W_MAX 10
#define HID 150
#define FD 20

#define PCOL 152            // P row stride (floats)
#define KP2 160             // padded K/N for the 150x150 layers

// ---- workspace layout (float offsets) ----
#define WS_ATTNS 0
#define WS_WE1   4096
#define WS_P     6144
#define WS_WPACK (6144 + 4 * 4096 * 152)     // = 2,496,512 floats (16B aligned)
// within wpack (ushort offsets): three 160x1024 state blocks, V 160x512,
// Wa2 160x160, Ws2 160x160
#define WP_A1  0
#define WP_S1A 163840
#define WP_S1B 327680
#define WP_V   491520
#define WP_A2  573440
#define WP_S2  599040
#define WP_TOTAL 624640     // = 160 * 3904

typedef short  bf16x8 __attribute__((ext_vector_type(8)));
typedef float  f32x4  __attribute__((ext_vector_type(4)));

__device__ __forceinline__ float4 ld4(const float* p) { return *(const float4*)p; }

__device__ __forceinline__ unsigned short f2bf(float f) {
    unsigned u = __float_as_uint(f);
    unsigned r = u + 0x7fffu + ((u >> 16) & 1u);   // RNE
    return (unsigned short)(r >> 16);
}

// build an A-frag (8 consecutive k) from fp32 memory
__device__ __forceinline__ bf16x8 cvt_frag(const float* p) {
    float4 u = ld4(p), v = ld4(p + 4);
    bf16x8 f;
    f[0] = (short)f2bf(u.x); f[1] = (short)f2bf(u.y);
    f[2] = (short)f2bf(u.z); f[3] = (short)f2bf(u.w);
    f[4] = (short)f2bf(v.x); f[5] = (short)f2bf(v.y);
    f[6] = (short)f2bf(v.z); f[7] = (short)f2bf(v.w);
    return f;
}

// ---------------------------------------------------------------------------
// Prepack: weights -> bf16, n-major [n][k], K padded. Coalesced READS
// (consecutive lanes -> consecutive n in the fp32 source); the scattered 2B
// writes land in the 1.2 MB L2-resident pack buffer (cheap).
// idx -> kk = idx/160 (global k), n = idx%160.
// ---------------------------------------------------------------------------
__global__ __launch_bounds__(256) void prepack_kernel(
    const float* __restrict__ Wa1, const float* __restrict__ Ws1,
    const float* __restrict__ Wa2, const float* __restrict__ Ws2,
    unsigned short* __restrict__ wp)
{
    int idx = blockIdx.x * 256 + threadIdx.x;
    if (idx >= WP_TOTAL) return;
    int kk = idx / KP2, n = idx % KP2;
    float v = 0.f;
    int dst;
    if (kk < 3072) {                          // three state blocks, K=1024
        int which = kk >> 10, k = kk & 1023;
        if (n < HID) {
            if (which == 0)      v = Wa1[(size_t)k * HID + n];
            else if (which == 1) v = Ws1[(size_t)k * HID + n];
            else                 v = Ws1[(size_t)(1024 + k) * HID + n];
        }
        dst = which * 163840 + n * 1024 + k;
    } else if (kk < 3584) {                   // V block, K=512
        int k = kk - 3072;
        if (n < HID) v = Ws1[(size_t)(2048 + k) * HID + n];
        dst = WP_V + n * 512 + k;
    } else if (kk < 3744) {                   // Wa2, K=160 (150 valid)
        int k = kk - 3584;
        if (n < HID && k < HID) v = Wa2[(size_t)k * HID + n];
        dst = WP_A2 + n * KP2 + k;
    } else {                                  // Ws2, K=160 (150 valid)
        int k = kk - 3744;
        if (n < HID && k < HID) v = Ws2[(size_t)k * HID + n];
        dst = WP_S2 + n * KP2 + k;
    }
    wp[dst] = f2bf(v);
}

// ---------------------------------------------------------------------------
// Token projections via MFMA, one wave per 16 token rows.
//   blockIdx.y == 0: states -> P0,P1,P2 (30 n-tiles, K=1024; states read ONCE)
//   blockIdx.y == 1: embeds -> P3      (10 n-tiles, K=512)
// No LDS, no barriers: A-frags cvt'd in-register, B-frags direct b128 loads.
// ---------------------------------------------------------------------------
__global__ __launch_bounds__(64) void token_gemm_kernel(
    const float* __restrict__ states, const float* __restrict__ embeds,
    const unsigned short* __restrict__ wp, float* __restrict__ P)
{
    const int lane = threadIdx.x, l15 = lane & 15, quad = lane >> 4;
    const int m0 = blockIdx.x * 16;

    if (blockIdx.y == 0) {
        f32x4 acc[30];
#pragma unroll
        for (int t = 0; t < 30; ++t)
#pragma unroll
            for (int i = 0; i < 4; ++i) acc[t][i] = 0.f;

        const float* a0 = states + (size_t)(m0 + l15) * 1024 + quad * 8;
        const unsigned short* bb = wp + l15 * 1024 + quad * 8;

        for (int k0 = 0; k0 < 1024; k0 += 32) {
            bf16x8 af = cvt_frag(a0 + k0);
#pragma unroll
            for (int t = 0; t < 30; ++t) {
                bf16x8 bf = *(const bf16x8*)(bb + (size_t)t * 16384 + k0);
                acc[t] = __builtin_amdgcn_mfma_f32_16x16x32_bf16(af, bf, acc[t], 0, 0, 0);
            }
        }
#pragma unroll
        for (int t = 0; t < 30; ++t) {
            int g = t / 10, col = (t % 10) * 16 + l15;
            if (col < PCOL) {
                float* Pg = P + (size_t)g * T_TOK * PCOL;
#pragma unroll
                for (int i = 0; i < 4; ++i)
                    Pg[(size_t)(m0 + quad * 4 + i) * PCOL + col] =
                        (col < HID) ? acc[t][i] : 0.f;
            }
        }
    } else {
        f32x4 acc[10];
#pragma unroll
        for (int t = 0; t < 10; ++t)
#pragma unroll
            for (int i = 0; i < 4; ++i) acc[t][i] = 0.f;

        const float* a0 = embeds + (size_t)(m0 + l15) * 512 + quad * 8;
        const unsigned short* bb = wp + WP_V + l15 * 512 + quad * 8;

        for (int k0 = 0; k0 < 512; k0 += 32) {
            bf16x8 af = cvt_frag(a0 + k0);
#pragma unroll
            for (int t = 0; t < 10; ++t) {
                bf16x8 bf = *(const bf16x8*)(bb + (size_t)t * 8192 + k0);
                acc[t] = __builtin_amdgcn_mfma_f32_16x16x32_bf16(af, bf, acc[t], 0, 0, 0);
            }
        }
        float* P3 = P + (size_t)3 * T_TOK * PCOL;
#pragma unroll
        for (int t = 0; t < 10; ++t) {
            int col = t * 16 + l15;
            if (col < PCOL) {
#pragma unroll
                for (int i = 0; i < 4; ++i)
                    P3[(size_t)(m0 + quad * 4 + i) * PCOL + col] =
                        (col < HID) ? acc[t][i] : 0.f;
            }
        }
    }
}

// ---------------------------------------------------------------------------
// WE1[9][152] = width_emb @ Ws1[2560:2580]  (tiny, fp32)
// ---------------------------------------------------------------------------
__global__ void we1_kernel(const float* __restrict__ width_emb,
                           const float* __restrict__ Ws1,
                           float* __restrict__ WE1)
{
    int idx = blockIdx.x * 256 + threadIdx.x;
    if (idx >= 9 * PCOL) return;
    int b = idx / PCOL, j = idx % PCOL;
    float acc = 0.f;
    if (j < HID) {
        for (int k = 0; k < FD; ++k)
            acc = fmaf(width_emb[b * FD + k], Ws1[(size_t)(2560 + k) * HID + j], acc);
    }
    WE1[idx] = acc;
}

// ---------------------------------------------------------------------------
// Attn tail: one wave per 16 tokens. h1 = relu(P0 + ba1) built in-register as
// A-frags; layer2 MFMA vs packed Wa2; layer3 via shuffle reduce. No LDS.
// ---------------------------------------------------------------------------
__global__ __launch_bounds__(64) void attn_tail_kernel(
    const float* __restrict__ P0, const float* __restrict__ ba1,
    const unsigned short* __restrict__ wp, const float* __restrict__ ba2,
    const float* __restrict__ Wa3, const float* __restrict__ ba3,
    float* __restrict__ attns)
{
    const int t0 = blockIdx.x * 16;
    const int lane = threadIdx.x, l15 = lane & 15, quad = lane >> 4;

    f32x4 acc[10];
#pragma unroll
    for (int nt = 0; nt < 10; ++nt)
#pragma unroll
        for (int i = 0; i < 4; ++i) acc[nt][i] = 0.f;

    const float* prow = P0 + (size_t)(t0 + l15) * PCOL;
    const unsigned short* bb = wp + WP_A2 + l15 * KP2 + quad * 8;

#pragma unroll
    for (int c = 0; c < 5; ++c) {
        const int k0 = c * 32;
        const int kk = k0 + quad * 8;
        bf16x8 af;
        if (kk < PCOL) {
            float4 u = ld4(prow + kk), v = ld4(prow + kk + 4);
            float x[8] = {u.x, u.y, u.z, u.w, v.x, v.y, v.z, v.w};
#pragma unroll
            for (int j = 0; j < 8; ++j) {
                float b = (kk + j < HID) ? ba1[kk + j] : 0.f;
                af[j] = (short)f2bf(fmaxf(x[j] + b, 0.f));
            }
        } else {
#pragma unroll
            for (int j = 0; j < 8; ++j) af[j] = 0;
        }
#pragma unroll
        for (int nt = 0; nt < 10; ++nt) {
            bf16x8 bf = *(const bf16x8*)(bb + nt * 16 * KP2 + k0);
            acc[nt] = __builtin_amdgcn_mfma_f32_16x16x32_bf16(af, bf, acc[nt], 0, 0, 0);
        }
    }

    float sc[4] = {0.f, 0.f, 0.f, 0.f};
#pragma unroll
    for (int nt = 0; nt < 10; ++nt) {
        int col = nt * 16 + l15;
        float w3 = (col < HID) ? Wa3[col] : 0.f;
        float b2 = (col < HID) ? ba2[col] : 0.f;
#pragma unroll
        for (int i = 0; i < 4; ++i)
            sc[i] = fmaf(fmaxf(acc[nt][i] + b2, 0.f), w3, sc[i]);
    }
#pragma unroll
    for (int off = 8; off >= 1; off >>= 1)
#pragma unroll
        for (int i = 0; i < 4; ++i) sc[i] += __shfl_down(sc[i], off, 16);
    if (l15 == 0) {
        float b3 = ba3[0];
#pragma unroll
        for (int i = 0; i < 4; ++i) attns[t0 + quad * 4 + i] = sc[i] + b3;
    }
}

// ---------------------------------------------------------------------------
// Span kernel: 64 spans/block. Gather-combine with COALESCED mapping:
// 4 lanes per span (s = tid>>2, jg = tid&3) -> each row read as contiguous
// 64 B per instruction, sequential c4 walk keeps lines L1-hot.
// Then layer2 MFMA + layer3 shuffle-reduce.
// ---------------------------------------------------------------------------
__global__ __launch_bounds__(256) void span_kernel(
    const float* __restrict__ P, const float* __restrict__ attns,
    const float* __restrict__ WE1, const unsigned short* __restrict__ wp,
    const int* __restrict__ span_starts, const int* __restrict__ span_widths,
    const float* __restrict__ bs1, const float* __restrict__ bs2,
    const float* __restrict__ Ws3, const float* __restrict__ bs3,
    float* __restrict__ out)
{
    __shared__ unsigned short sHb[64][168];   // h1 bf16, stride 168 (16B-aligned rows)
    __shared__ float s_wgt[64][W_MAX];
    __shared__ short s_pos[64][W_MAX];
    __shared__ short s_start[64], s_end[64], s_bin[64], s_wd[64];
    __shared__ float sPart[4][64];
    __shared__ float sb1[PCOL];

    const int tid = threadIdx.x;
    const int n0s = blockIdx.x * 64;

    if (tid < PCOL) sb1[tid] = (tid < HID) ? bs1[tid] : 0.f;
    if (tid < 64) {
        int st = span_starts[n0s + tid];
        int wd = span_widths[n0s + tid];
        s_start[tid] = (short)st;
        s_end[tid] = (short)(st + wd - 1);
        s_wd[tid] = (short)wd;
        s_bin[tid] = (short)((wd >= 1) + (wd >= 2) + (wd >= 3) + (wd >= 4) +
                             (wd >= 8) + (wd >= 16) + (wd >= 32) + (wd >= 64));
        float lg[W_MAX];
        float m = -1e30f;
#pragma unroll
        for (int w = 0; w < W_MAX; ++w)
            if (w < wd) { float a = attns[st + w]; lg[w] = a; m = fmaxf(m, a); }
        float sum = 0.f;
#pragma unroll
        for (int w = 0; w < W_MAX; ++w) {
            float e = (w < wd) ? __expf(lg[w] - m) : 0.f;
            lg[w] = e; sum += e;
        }
        float inv = 1.f / sum;
#pragma unroll
        for (int w = 0; w < W_MAX; ++w) {
            s_wgt[tid][w] = lg[w] * inv;
            s_pos[tid][w] = (short)(st + w);
        }
        // zero the k-pad (cols 152..159)
        ushort4 z = {0, 0, 0, 0};
        *(ushort4*)&sHb[tid][152] = z;
        *(ushort4*)&sHb[tid][156] = z;
    }
    __syncthreads();

    // gather-combine (fp32) -> relu -> bf16 into sHb[span][k]
    {
        const float* P1 = P + (size_t)1 * T_TOK * PCOL;
        const float* P2 = P + (size_t)2 * T_TOK * PCOL;
        const float* P3 = P + (size_t)3 * T_TOK * PCOL;
        const int s = tid >> 2;          // span 0..63 (4 lanes each)
        const int jg = tid & 3;          // col-chunk group
        const int rs = (int)s_start[s] * PCOL;
        const int re = (int)s_end[s] * PCOL;
        const int rb = (int)s_bin[s] * PCOL;
        const int wd = s_wd[s];
        for (int c4 = jg; c4 < PCOL / 4; c4 += 4) {
            const int j = 4 * c4;
            float4 a = ld4(P1 + rs + j);
            float4 b = ld4(P2 + re + j);
            float4 c = ld4(WE1 + rb + j);
            float acc[4];
            acc[0] = a.x + b.x + c.x + sb1[j + 0];
            acc[1] = a.y + b.y + c.y + sb1[j + 1];
            acc[2] = a.z + b.z + c.z + sb1[j + 2];
            acc[3] = a.w + b.w + c.w + sb1[j + 3];
#pragma unroll
            for (int w = 0; w < W_MAX; ++w) {
                if (w < wd) {
                    float wt = s_wgt[s][w];
                    const float* ep = P3 + (int)s_pos[s][w] * PCOL + j;
                    float4 v = ld4(ep);
                    acc[0] = fmaf(wt, v.x, acc[0]);
                    acc[1] = fmaf(wt, v.y, acc[1]);
                    acc[2] = fmaf(wt, v.z, acc[2]);
                    acc[3] = fmaf(wt, v.w, acc[3]);
                }
            }
            ushort4 pk;
            pk.x = f2bf(fmaxf(acc[0], 0.f));
            pk.y = f2bf(fmaxf(acc[1], 0.f));
            pk.z = f2bf(fmaxf(acc[2], 0.f));
            pk.w = f2bf(fmaxf(acc[3], 0.f));
            *(ushort4*)&sHb[s][j] = pk;
        }
    }
    __syncthreads();

    // layer2 MFMA: M=64 (4 m-tiles), N=160 (10 n-tiles split over 4 waves)
    const int wv = tid >> 6;
    const int lane = tid & 63, l15 = lane & 15, quad = lane >> 4;
    const int ntb = (wv < 2) ? 3 * wv : 6 + 2 * (wv - 2);
    const int cnt = (wv < 2) ? 3 : 2;

    f32x4 acc2[4][3];
#pragma unroll
    for (int mt = 0; mt < 4; ++mt)
#pragma unroll
        for (int t = 0; t < 3; ++t)
#pragma unroll
            for (int i = 0; i < 4; ++i) acc2[mt][t][i] = 0.f;

    const unsigned short* bb = wp + WP_S2 + l15 * KP2 + quad * 8;

#pragma unroll
    for (int c = 0; c < 5; ++c) {
        const int k0 = c * 32;
        bf16x8 afr[4];
#pragma unroll
        for (int mt = 0; mt < 4; ++mt)
            afr[mt] = *(const bf16x8*)&sHb[mt * 16 + l15][k0 + quad * 8];
        for (int t = 0; t < cnt; ++t) {
            bf16x8 bfr = *(const bf16x8*)(bb + (ntb + t) * 16 * KP2 + k0);
#pragma unroll
            for (int mt = 0; mt < 4; ++mt)
                acc2[mt][t] = __builtin_amdgcn_mfma_f32_16x16x32_bf16(afr[mt], bfr, acc2[mt][t], 0, 0, 0);
        }
    }

    // layer3: relu(acc2 + bs2) . Ws3, partial per wave
    float sc[4][4];
#pragma unroll
    for (int mt = 0; mt < 4; ++mt)
#pragma unroll
        for (int i = 0; i < 4; ++i) sc[mt][i] = 0.f;

    for (int t = 0; t < cnt; ++t) {
        int col = (ntb + t) * 16 + l15;
        float w3 = (col < HID) ? Ws3[col] : 0.f;
        float b2 = (col < HID) ? bs2[col] : 0.f;
#pragma unroll
        for (int mt = 0; mt < 4; ++mt)
#pragma unroll
            for (int i = 0; i < 4; ++i)
                sc[mt][i] = fmaf(fmaxf(acc2[mt][t][i] + b2, 0.f), w3, sc[mt][i]);
    }
#pragma unroll
    for (int off = 8; off >= 1; off >>= 1)
#pragma unroll
        for (int mt = 0; mt < 4; ++mt)
#pragma unroll
            for (int i = 0; i < 4; ++i)
                sc[mt][i] += __shfl_down(sc[mt][i], off, 16);
    if (l15 == 0) {
#pragma unroll
        for (int mt = 0; mt < 4; ++mt)
#pragma unroll
            for (int i = 0; i < 4; ++i)
                sPart[wv][mt * 16 + quad * 4 + i] = sc[mt][i];
    }
    __syncthreads();
    if (tid < 64)
        out[n0s + tid] = sPart[0][tid] + sPart[1][tid] + sPart[2][tid] + sPart[3][tid] + bs3[0];
}

// ---------------------------------------------------------------------------
extern "C" void kernel_launch(void* const* d_in, const int* in_sizes, int n_in,
                              void* d_out, int out_size, void* d_ws, size_t ws_size,
                              hipStream_t stream)
{
    const float* states      = (const float*)d_in[0];
    const float* embeds      = (const float*)d_in[1];
    const int*   span_starts = (const int*)d_in[2];
    const int*   span_widths = (const int*)d_in[3];
    const float* Wa1 = (const float*)d_in[4];
    const float* ba1 = (const float*)d_in[5];
    const float* Wa2 = (const float*)d_in[6];
    const float* ba2 = (const float*)d_in[7];
    const float* Wa3 = (const float*)d_in[8];
    const float* ba3 = (const float*)d_in[9];
    const float* width_emb = (const float*)d_in[10];
    const float* Ws1 = (const float*)d_in[11];
    const float* bs1 = (const float*)d_in[12];
    const float* Ws2 = (const float*)d_in[13];
    const float* bs2 = (const float*)d_in[14];
    const float* Ws3 = (const float*)d_in[15];
    const float* bs3 = (const float*)d_in[16];
    float* out = (float*)d_out;

    float* ws    = (float*)d_ws;
    float* attns = ws + WS_ATTNS;
    float* WE1   = ws + WS_WE1;
    float* P     = ws + WS_P;
    unsigned short* wpack = (unsigned short*)(ws + WS_WPACK);

    hipLaunchKernelGGL(prepack_kernel, dim3((WP_TOTAL + 255) / 256), dim3(256), 0, stream,
                       Wa1, Ws1, Wa2, Ws2, wpack);
    hipLaunchKernelGGL(token_gemm_kernel, dim3(T_TOK / 16, 2), dim3(64), 0, stream,
                       states, embeds, wpack, P);
    hipLaunchKernelGGL(we1_kernel, dim3(6), dim3(256), 0, stream,
                       width_emb, Ws1, WE1);
    hipLaunchKernelGGL(attn_tail_kernel, dim3(T_TOK / 16), dim3(64), 0, stream,
                       P, ba1, wpack, ba2, Wa3, ba3, attns);
    hipLaunchKernelGGL(span_kernel, dim3(N_SPAN / 64), dim3(256), 0, stream,
                       P, attns, WE1, wpack, span_starts, span_widths,
                       bs1, bs2, Ws3, bs3, out);
}

// Round 5
// 178.931 us; speedup vs baseline: 1.2839x; 1.2839x over previous
//
#include <hip/hip_runtime.h>
#include <math.h>

#define T_TOK 4096
#define A_DIM 1024
#define E_DIM 512
#define N_SPAN 32768
#define W_MAX 10
#define HID 150
#define FD 20

#define PR  160             // P row stride (bf16 elems); cols 150..159 zero
#define KP2 160             // padded K/N for the 150x150 layers

// ---- workspace layout (float offsets) ----
#define WS_ATTNS 0
#define WS_PB    4096                    // 3 x 4096 x 160 ushort = 983,040 floats
#define WS_WPACK (4096 + 983040)
// Pb ushort offsets
#define PB_P1 0
#define PB_P2 655360
#define PB_P3 1310720
// wpack ushort offsets
#define WP_A1  0
#define WP_S1A 163840
#define WP_S1B 327680
#define WP_V   491520
#define WP_A2  573440
#define WP_S2  599040
#define WP_WE1 624640
#define WP_TOTAL 626080

typedef short  bf16x8 __attribute__((ext_vector_type(8)));
typedef float  f32x4  __attribute__((ext_vector_type(4)));

__device__ __forceinline__ float4 ld4(const float* p) { return *(const float4*)p; }

__device__ __forceinline__ unsigned short f2bf(float f) {
    unsigned u = __float_as_uint(f);
    unsigned r = u + 0x7fffu + ((u >> 16) & 1u);   // RNE
    return (unsigned short)(r >> 16);
}
__device__ __forceinline__ float bf2f(short s) {
    return __uint_as_float(((unsigned)(unsigned short)s) << 16);
}

// build an A-frag (8 consecutive k) from fp32 memory
__device__ __forceinline__ bf16x8 cvt_frag(const float* p) {
    float4 u = ld4(p), v = ld4(p + 4);
    bf16x8 f;
    f[0] = (short)f2bf(u.x); f[1] = (short)f2bf(u.y);
    f[2] = (short)f2bf(u.z); f[3] = (short)f2bf(u.w);
    f[4] = (short)f2bf(v.x); f[5] = (short)f2bf(v.y);
    f[6] = (short)f2bf(v.z); f[7] = (short)f2bf(v.w);
    return f;
}

// ---------------------------------------------------------------------------
// Prepack: weights -> bf16 n-major [n][k] + WE1 = width_emb @ Ws1[2560:] (bf16).
// Coalesced fp32 reads; scattered 2B writes land in the L2-resident pack.
// ---------------------------------------------------------------------------
__global__ __launch_bounds__(256) void prepack_kernel(
    const float* __restrict__ Wa1, const float* __restrict__ Ws1,
    const float* __restrict__ Wa2, const float* __restrict__ Ws2,
    const float* __restrict__ width_emb, unsigned short* __restrict__ wp)
{
    int idx = blockIdx.x * 256 + threadIdx.x;
    if (idx >= WP_TOTAL) return;
    if (idx < WP_WE1) {
        int kk = idx / KP2, n = idx % KP2;
        float v = 0.f;
        int dst;
        if (kk < 3072) {                          // Wa1 / Ws1a / Ws1b, K=1024
            int which = kk >> 10, k = kk & 1023;
            if (n < HID) {
                if (which == 0)      v = Wa1[(size_t)k * HID + n];
                else if (which == 1) v = Ws1[(size_t)k * HID + n];
                else                 v = Ws1[(size_t)(1024 + k) * HID + n];
            }
            dst = which * 163840 + n * 1024 + k;
        } else if (kk < 3584) {                   // V block, K=512
            int k = kk - 3072;
            if (n < HID) v = Ws1[(size_t)(2048 + k) * HID + n];
            dst = WP_V + n * 512 + k;
        } else if (kk < 3744) {                   // Wa2
            int k = kk - 3584;
            if (n < HID && k < HID) v = Wa2[(size_t)k * HID + n];
            dst = WP_A2 + n * KP2 + k;
        } else {                                  // Ws2
            int k = kk - 3744;
            if (n < HID && k < HID) v = Ws2[(size_t)k * HID + n];
            dst = WP_S2 + n * KP2 + k;
        }
        wp[dst] = f2bf(v);
    } else {                                      // WE1[9][160] bf16
        int e = idx - WP_WE1;
        int b = e / KP2, n = e % KP2;
        float acc = 0.f;
        if (n < HID) {
            for (int k = 0; k < FD; ++k)
                acc = fmaf(width_emb[b * FD + k], Ws1[(size_t)(2560 + k) * HID + n], acc);
        }
        wp[idx] = f2bf(acc);
    }
}

// ---------------------------------------------------------------------------
// Token kernel, grid = 384 blocks x 256 threads (4 waves):
//  bid < 256 : states-block, M=16 rows x 30 n-tiles (Wa1|Ws1a|Ws1b), split
//              8/8/7/7 across waves; g0 result kept in LDS, fused attn-MLP
//              tail -> attns[16]; g1/g2 stored to P1/P2 (bf16).
//  bid >= 256: embeds-block, M=32 rows x 10 n-tiles (V) -> P3 (bf16).
// No LDS staging for GEMM inputs: A cvt'd in-register (waves share rows via
// L1), B direct b128 from the packed weights (XCD-L2 resident).
// ---------------------------------------------------------------------------
__global__ __launch_bounds__(256) void token_kernel(
    const float* __restrict__ states, const float* __restrict__ embeds,
    const unsigned short* __restrict__ wp,
    const float* __restrict__ ba1, const float* __restrict__ ba2,
    const float* __restrict__ Wa3, const float* __restrict__ ba3,
    unsigned short* __restrict__ Pb, float* __restrict__ attns)
{
    __shared__ unsigned short h1a[16][168];
    __shared__ float sPartA[4][16];
    const int tid = threadIdx.x;
    const int wv = tid >> 6, lane = tid & 63, l15 = lane & 15, quad = lane >> 4;

    if (blockIdx.x < 256) {
        const int m0 = blockIdx.x * 16;
        const int t0 = (wv < 2) ? wv * 8 : 16 + (wv - 2) * 7;   // 8,8,7,7
        const int tcnt = (wv < 2) ? 8 : 7;

        f32x4 acc[8];
#pragma unroll
        for (int t = 0; t < 8; ++t)
#pragma unroll
            for (int i = 0; i < 4; ++i) acc[t][i] = 0.f;

        const float* a0 = states + (size_t)(m0 + l15) * A_DIM + quad * 8;
        const unsigned short* bb[8];
#pragma unroll
        for (int tt = 0; tt < 8; ++tt) {
            int t = t0 + ((tt < tcnt) ? tt : 0);
            bb[tt] = wp + (size_t)(t / 10) * 163840 +
                     (size_t)((t % 10) * 16 + l15) * 1024 + quad * 8;
        }
        for (int k0 = 0; k0 < A_DIM; k0 += 32) {
            bf16x8 af = cvt_frag(a0 + k0);
#pragma unroll
            for (int tt = 0; tt < 8; ++tt) {
                if (tt < tcnt) {
                    bf16x8 b = *(const bf16x8*)(bb[tt] + k0);
                    acc[tt] = __builtin_amdgcn_mfma_f32_16x16x32_bf16(af, b, acc[tt], 0, 0, 0);
                }
            }
        }
#pragma unroll
        for (int tt = 0; tt < 8; ++tt) {
            if (tt < tcnt) {
                int t = t0 + tt, g = t / 10, col = (t % 10) * 16 + l15;
                if (g == 0) {
                    float b = (col < HID) ? ba1[col] : 0.f;
#pragma unroll
                    for (int i = 0; i < 4; ++i)
                        h1a[quad * 4 + i][col] = f2bf(fmaxf(acc[tt][i] + b, 0.f));
                } else {
                    unsigned short* Pg = Pb + (size_t)(g - 1) * 655360;
#pragma unroll
                    for (int i = 0; i < 4; ++i)
                        Pg[(size_t)(m0 + quad * 4 + i) * PR + col] =
                            (col < HID) ? f2bf(acc[tt][i]) : (unsigned short)0;
                }
            }
        }
        __syncthreads();

        // fused attn-MLP tail: tiles 3,3,2,2 over waves
        const int nb = (wv < 2) ? wv * 3 : 6 + (wv - 2) * 2;
        const int ncnt = (wv < 2) ? 3 : 2;
        f32x4 a2[3];
#pragma unroll
        for (int t = 0; t < 3; ++t)
#pragma unroll
            for (int i = 0; i < 4; ++i) a2[t][i] = 0.f;
#pragma unroll
        for (int c = 0; c < 5; ++c) {
            int k0 = c * 32;
            bf16x8 afr = *(const bf16x8*)&h1a[l15][k0 + quad * 8];
#pragma unroll
            for (int t = 0; t < 3; ++t) {
                if (t < ncnt) {
                    bf16x8 b = *(const bf16x8*)(wp + WP_A2 +
                                (size_t)((nb + t) * 16 + l15) * KP2 + k0 + quad * 8);
                    a2[t] = __builtin_amdgcn_mfma_f32_16x16x32_bf16(afr, b, a2[t], 0, 0, 0);
                }
            }
        }
        float sc[4] = {0.f, 0.f, 0.f, 0.f};
#pragma unroll
        for (int t = 0; t < 3; ++t) {
            if (t < ncnt) {
                int col = (nb + t) * 16 + l15;
                float w3 = (col < HID) ? Wa3[col] : 0.f;
                float b2 = (col < HID) ? ba2[col] : 0.f;
#pragma unroll
                for (int i = 0; i < 4; ++i)
                    sc[i] = fmaf(fmaxf(a2[t][i] + b2, 0.f), w3, sc[i]);
            }
        }
#pragma unroll
        for (int off = 8; off >= 1; off >>= 1)
#pragma unroll
            for (int i = 0; i < 4; ++i) sc[i] += __shfl_down(sc[i], off, 16);
        if (l15 == 0) {
#pragma unroll
            for (int i = 0; i < 4; ++i) sPartA[wv][quad * 4 + i] = sc[i];
        }
        __syncthreads();
        if (tid < 16)
            attns[m0 + tid] = sPartA[0][tid] + sPartA[1][tid] +
                              sPartA[2][tid] + sPartA[3][tid] + ba3[0];
    } else {
        const int m0 = (blockIdx.x - 256) * 32;
        const int mh = wv & 1, hf = wv >> 1;
        const int t0 = hf * 5;
        f32x4 acc[5];
#pragma unroll
        for (int t = 0; t < 5; ++t)
#pragma unroll
            for (int i = 0; i < 4; ++i) acc[t][i] = 0.f;

        const float* a0 = embeds + (size_t)(m0 + mh * 16 + l15) * E_DIM + quad * 8;
        for (int k0 = 0; k0 < E_DIM; k0 += 32) {
            bf16x8 af = cvt_frag(a0 + k0);
#pragma unroll
            for (int tt = 0; tt < 5; ++tt) {
                bf16x8 b = *(const bf16x8*)(wp + WP_V +
                            (size_t)((t0 + tt) * 16 + l15) * 512 + k0 + quad * 8);
                acc[tt] = __builtin_amdgcn_mfma_f32_16x16x32_bf16(af, b, acc[tt], 0, 0, 0);
            }
        }
        unsigned short* P3 = Pb + PB_P3;
#pragma unroll
        for (int tt = 0; tt < 5; ++tt) {
            int col = (t0 + tt) * 16 + l15;
#pragma unroll
            for (int i = 0; i < 4; ++i)
                P3[(size_t)(m0 + mh * 16 + quad * 4 + i) * PR + col] =
                    (col < HID) ? f2bf(acc[tt][i]) : (unsigned short)0;
        }
    }
}

// ---------------------------------------------------------------------------
// Span kernel: 32 spans/block, grid 1024 (16 waves/CU resident).
// Gather-combine from bf16 P (XCD-L2 resident) -> h1 bf16 in LDS;
// layer2 MFMA (B direct from packed Ws2); layer3 shuffle-reduce.
// ---------------------------------------------------------------------------
__global__ __launch_bounds__(256) void span_kernel(
    const unsigned short* __restrict__ Pb, const float* __restrict__ attns,
    const unsigned short* __restrict__ wp,
    const int* __restrict__ span_starts, const int* __restrict__ span_widths,
    const float* __restrict__ bs1, const float* __restrict__ bs2,
    const float* __restrict__ Ws3, const float* __restrict__ bs3,
    float* __restrict__ out)
{
    __shared__ unsigned short sHb[32][168];
    __shared__ float s_wgt[32][W_MAX];
    __shared__ int s_st[32], s_wd[32], s_bin[32];
    __shared__ float sPart[4][32];
    __shared__ float sb1[KP2];

    const int tid = threadIdx.x;
    const int n0s = blockIdx.x * 32;

    if (tid < KP2) sb1[tid] = (tid < HID) ? bs1[tid] : 0.f;
    if (tid < 32) {
        int st = span_starts[n0s + tid], wd = span_widths[n0s + tid];
        s_st[tid] = st; s_wd[tid] = wd;
        s_bin[tid] = (wd >= 1) + (wd >= 2) + (wd >= 3) + (wd >= 4) +
                     (wd >= 8) + (wd >= 16) + (wd >= 32) + (wd >= 64);
        float lg[W_MAX];
        float m = -1e30f;
#pragma unroll
        for (int w = 0; w < W_MAX; ++w)
            if (w < wd) { float a = attns[st + w]; lg[w] = a; m = fmaxf(m, a); }
        float sum = 0.f;
#pragma unroll
        for (int w = 0; w < W_MAX; ++w) {
            float e = (w < wd) ? __expf(lg[w] - m) : 0.f;
            lg[w] = e; sum += e;
        }
        float inv = 1.f / sum;
#pragma unroll
        for (int w = 0; w < W_MAX; ++w) s_wgt[tid][w] = lg[w] * inv;
    }
    __syncthreads();

    // gather-combine: 8 lanes/span, 16-B bf16x8 chunks (8 cols each)
    {
        const unsigned short* P1b = Pb + PB_P1;
        const unsigned short* P2b = Pb + PB_P2;
        const unsigned short* P3b = Pb + PB_P3;
        const unsigned short* WEb = wp + WP_WE1;
        const int s = tid >> 3, jl = tid & 7;
        const int st = s_st[s], wd = s_wd[s];
        const size_t rs = (size_t)st * PR;
        const size_t re = (size_t)(st + wd - 1) * PR;
        const size_t rb = (size_t)s_bin[s] * PR;
        for (int c = jl; c < 20; c += 8) {
            const int j = c * 8;
            bf16x8 u1 = *(const bf16x8*)(P1b + rs + j);
            bf16x8 u2 = *(const bf16x8*)(P2b + re + j);
            bf16x8 uw = *(const bf16x8*)(WEb + rb + j);
            float acc[8];
#pragma unroll
            for (int i = 0; i < 8; ++i)
                acc[i] = bf2f(u1[i]) + bf2f(u2[i]) + bf2f(uw[i]) + sb1[j + i];
#pragma unroll
            for (int w = 0; w < W_MAX; ++w) {
                if (w < wd) {
                    float wt = s_wgt[s][w];
                    bf16x8 uv = *(const bf16x8*)(P3b + rs + (size_t)w * PR + j);
#pragma unroll
                    for (int i = 0; i < 8; ++i)
                        acc[i] = fmaf(wt, bf2f(uv[i]), acc[i]);
                }
            }
            bf16x8 pk;
#pragma unroll
            for (int i = 0; i < 8; ++i) pk[i] = (short)f2bf(fmaxf(acc[i], 0.f));
            *(bf16x8*)&sHb[s][j] = pk;
        }
    }
    __syncthreads();

    // layer2 MFMA: M=32 (2 m-tiles), N=160 (tiles 3,3,2,2 over waves)
    const int wv = tid >> 6, lane = tid & 63, l15 = lane & 15, quad = lane >> 4;
    const int nb = (wv < 2) ? wv * 3 : 6 + (wv - 2) * 2;
    const int cnt = (wv < 2) ? 3 : 2;

    f32x4 a2[2][3];
#pragma unroll
    for (int mt = 0; mt < 2; ++mt)
#pragma unroll
        for (int t = 0; t < 3; ++t)
#pragma unroll
            for (int i = 0; i < 4; ++i) a2[mt][t][i] = 0.f;

#pragma unroll
    for (int c = 0; c < 5; ++c) {
        int k0 = c * 32;
        bf16x8 af0 = *(const bf16x8*)&sHb[l15][k0 + quad * 8];
        bf16x8 af1 = *(const bf16x8*)&sHb[16 + l15][k0 + quad * 8];
#pragma unroll
        for (int t = 0; t < 3; ++t) {
            if (t < cnt) {
                bf16x8 b = *(const bf16x8*)(wp + WP_S2 +
                            (size_t)((nb + t) * 16 + l15) * KP2 + k0 + quad * 8);
                a2[0][t] = __builtin_amdgcn_mfma_f32_16x16x32_bf16(af0, b, a2[0][t], 0, 0, 0);
                a2[1][t] = __builtin_amdgcn_mfma_f32_16x16x32_bf16(af1, b, a2[1][t], 0, 0, 0);
            }
        }
    }

    float sc[2][4];
#pragma unroll
    for (int mt = 0; mt < 2; ++mt)
#pragma unroll
        for (int i = 0; i < 4; ++i) sc[mt][i] = 0.f;
#pragma unroll
    for (int t = 0; t < 3; ++t) {
        if (t < cnt) {
            int col = (nb + t) * 16 + l15;
            float w3 = (col < HID) ? Ws3[col] : 0.f;
            float b2 = (col < HID) ? bs2[col] : 0.f;
#pragma unroll
            for (int mt = 0; mt < 2; ++mt)
#pragma unroll
                for (int i = 0; i < 4; ++i)
                    sc[mt][i] = fmaf(fmaxf(a2[mt][t][i] + b2, 0.f), w3, sc[mt][i]);
        }
    }
#pragma unroll
    for (int off = 8; off >= 1; off >>= 1)
#pragma unroll
        for (int mt = 0; mt < 2; ++mt)
#pragma unroll
            for (int i = 0; i < 4; ++i)
                sc[mt][i] += __shfl_down(sc[mt][i], off, 16);
    if (l15 == 0) {
#pragma unroll
        for (int mt = 0; mt < 2; ++mt)
#pragma unroll
            for (int i = 0; i < 4; ++i)
                sPart[wv][mt * 16 + quad * 4 + i] = sc[mt][i];
    }
    __syncthreads();
    if (tid < 32)
        out[n0s + tid] = sPart[0][tid] + sPart[1][tid] + sPart[2][tid] +
                         sPart[3][tid] + bs3[0];
}

// ---------------------------------------------------------------------------
extern "C" void kernel_launch(void* const* d_in, const int* in_sizes, int n_in,
                              void* d_out, int out_size, void* d_ws, size_t ws_size,
                              hipStream_t stream)
{
    const float* states      = (const float*)d_in[0];
    const float* embeds      = (const float*)d_in[1];
    const int*   span_starts = (const int*)d_in[2];
    const int*   span_widths = (const int*)d_in[3];
    const float* Wa1 = (const float*)d_in[4];
    const float* ba1 = (const float*)d_in[5];
    const float* Wa2 = (const float*)d_in[6];
    const float* ba2 = (const float*)d_in[7];
    const float* Wa3 = (const float*)d_in[8];
    const float* ba3 = (const float*)d_in[9];
    const float* width_emb = (const float*)d_in[10];
    const float* Ws1 = (const float*)d_in[11];
    const float* bs1 = (const float*)d_in[12];
    const float* Ws2 = (const float*)d_in[13];
    const float* bs2 = (const float*)d_in[14];
    const float* Ws3 = (const float*)d_in[15];
    const float* bs3 = (const float*)d_in[16];
    float* out = (float*)d_out;

    float* ws    = (float*)d_ws;
    float* attns = ws + WS_ATTNS;
    unsigned short* Pb    = (unsigned short*)(ws + WS_PB);
    unsigned short* wpack = (unsigned short*)(ws + WS_WPACK);

    hipLaunchKernelGGL(prepack_kernel, dim3((WP_TOTAL + 255) / 256), dim3(256), 0, stream,
                       Wa1, Ws1, Wa2, Ws2, width_emb, wpack);
    hipLaunchKernelGGL(token_kernel, dim3(384), dim3(256), 0, stream,
                       states, embeds, wpack, ba1, ba2, Wa3, ba3, Pb, attns);
    hipLaunchKernelGGL(span_kernel, dim3(N_SPAN / 32), dim3(256), 0, stream,
                       Pb, attns, wpack, span_starts, span_widths,
                       bs1, bs2, Ws3, bs3, out);
}